// Round 7
// baseline (519.893 us; speedup 1.0000x reference)
//
#include <hip/hip_runtime.h>
#include <hip/hip_bf16.h>
#include <stdint.h>

#define V 200000
#define E 600000
#define NB1 782          // ceil(V/256)
#define NSTRIP 12500     // V/16

using bf16x8_t = __attribute__((ext_vector_type(8))) short;
using f32x4_t  = __attribute__((ext_vector_type(4))) float;

__device__ __forceinline__ unsigned short f2bf(float f) {
  __hip_bfloat16 h = __float2bfloat16(f);
  return *reinterpret_cast<unsigned short*>(&h);
}
__device__ __forceinline__ float bf_lo(unsigned d) { return __uint_as_float(d << 16); }
__device__ __forceinline__ float bf_hi(unsigned d) { return __uint_as_float(d & 0xffff0000u); }

__device__ __forceinline__ bf16x8_t pack8(const float4& q0, const float4& q1) {
  union { __hip_bfloat162 h[4]; bf16x8_t v; } p;
  float2 t;
  t.x = q0.x; t.y = q0.y; p.h[0] = __float22bfloat162_rn(t);
  t.x = q0.z; t.y = q0.w; p.h[1] = __float22bfloat162_rn(t);
  t.x = q1.x; t.y = q1.y; p.h[2] = __float22bfloat162_rn(t);
  t.x = q1.z; t.y = q1.w; p.h[3] = __float22bfloat162_rn(t);
  return p.v;
}

// ---------------------------------------------------------------------------
// prep_w3: fragment-LINEAR weights for the n-outer/kg-inner MFMA loop.
//   o = ((cg*8 + kg)*64 + lane)*8 + e  maps to W[c][k],
//   c = cg*16 + (lane&15)  (c<256 -> w0, else w1),  k = kg*32 + (lane>>4)*8 + e.
// Consecutive MFMA fragments are consecutive 1KB blocks (single pointer walk).
// ---------------------------------------------------------------------------
__global__ void prep_w3(const float* __restrict__ w0, const float* __restrict__ w1,
                        unsigned short* __restrict__ Wb) {
  int o = blockIdx.x * 256 + threadIdx.x;        // 0..98303
  int e    = o & 7;
  int lane = (o >> 3) & 63;
  int kg   = (o >> 9) & 7;
  int cg   = o >> 12;                            // 0..23
  int c = cg * 16 + (lane & 15);
  int k = kg * 32 + (lane >> 4) * 8 + e;
  float v = (c < 256) ? w0[c * 256 + k] : w1[(c - 256) * 256 + k];
  Wb[o] = f2bf(v);
}

// ---------------------------------------------------------------------------
// gemm_all: out[V,256] = verts@w0^T + b0 (fp32), w1b[V,128] = bf16(verts@w1^T+b1)
// Persistent grid-stride waves; wave = 16 rows x all 384 cols. Cross-strip
// pipeline: next strip's 16 dwordx4 A loads issued before the MFMA n-loop.
// B = linear 1KB-fragment walk over Wb3 (L2-resident). No LDS, no barriers.
// ---------------------------------------------------------------------------
__global__ __launch_bounds__(256, 4) void gemm_all(
    const float* __restrict__ verts, const unsigned short* __restrict__ Wb3,
    const float* __restrict__ w0_b, const float* __restrict__ w1_b,
    float* __restrict__ out, unsigned short* __restrict__ w1b)
{
  const int tid = threadIdx.x, lane = tid & 63;
  const int wid = blockIdx.x * 4 + (tid >> 6);
  const int nw  = gridDim.x * 4;
  const int l15 = lane & 15, lq = lane >> 4;
  const unsigned short* bbase = Wb3 + lane * 8;

  int strip = wid;
  if (strip >= NSTRIP) return;

  float4 q[16];
  {
    const float* vp = verts + ((size_t)strip * 16 + l15) * 256 + lq * 8;
    #pragma unroll
    for (int kg = 0; kg < 8; ++kg) {
      q[2*kg]   = *(const float4*)(vp + kg * 32);
      q[2*kg+1] = *(const float4*)(vp + kg * 32 + 4);
    }
  }

  while (true) {
    const int next = strip + nw;

    bf16x8_t af[8];
    #pragma unroll
    for (int kg = 0; kg < 8; ++kg) af[kg] = pack8(q[2*kg], q[2*kg+1]);

    if (next < NSTRIP) {                   // prefetch next strip's A tile
      const float* vn = verts + ((size_t)next * 16 + l15) * 256 + lq * 8;
      #pragma unroll
      for (int kg = 0; kg < 8; ++kg) {
        q[2*kg]   = *(const float4*)(vn + kg * 32);
        q[2*kg+1] = *(const float4*)(vn + kg * 32 + 4);
      }
    }

    const int rBase = strip * 16;
    const unsigned short* bp = bbase;

    float* orow = out + (size_t)(rBase + lq * 4) * 256 + l15;
    #pragma unroll 2
    for (int n = 0; n < 16; ++n) {         // w0 region: frags 8n..8n+7
      f32x4_t acc = (f32x4_t){0.f, 0.f, 0.f, 0.f};
      #pragma unroll
      for (int kg = 0; kg < 8; ++kg) {
        acc = __builtin_amdgcn_mfma_f32_16x16x32_bf16(
            af[kg], *(const bf16x8_t*)bp, acc, 0, 0, 0);
        bp += 512;
      }
      float bias = w0_b[n * 16 + l15];
      #pragma unroll
      for (int r = 0; r < 4; ++r)
        orow[(size_t)r * 256 + n * 16] = acc[r] + bias;
    }

    unsigned short* wrow = w1b + (size_t)(rBase + lq * 4) * 128 + l15;
    #pragma unroll 2
    for (int n = 0; n < 8; ++n) {          // w1 region: frags 128+8n..
      f32x4_t acc = (f32x4_t){0.f, 0.f, 0.f, 0.f};
      #pragma unroll
      for (int kg = 0; kg < 8; ++kg) {
        acc = __builtin_amdgcn_mfma_f32_16x16x32_bf16(
            af[kg], *(const bf16x8_t*)bp, acc, 0, 0, 0);
        bp += 512;
      }
      float bias = w1_b[n * 16 + l15];
      #pragma unroll
      for (int r = 0; r < 4; ++r)
        wrow[(size_t)r * 128 + n * 16] = f2bf(acc[r] + bias);
    }

    if (next >= NSTRIP) break;
    strip = next;
  }
}

// ---------------------------------------------------------------------------
// gather_rmw: out[r, 0:128] += sum_{u in adj[r]} w1b[u].
// Wave = 4 rows (one per 16-lane group). Each group-load fetches a FULL 256B
// w1b row (16 lanes x 16B). Neighbor index prefetched one step ahead -> one
// latency per neighbor. out row-chunk read issued before the gather.
// ~30 VGPR -> 32 waves/CU of MLP.
// ---------------------------------------------------------------------------
__global__ __launch_bounds__(256, 8) void gather_rmw(
    const int* __restrict__ rowptr, const int* __restrict__ adj,
    const unsigned short* __restrict__ w1b, float* __restrict__ out)
{
  const int tid = threadIdx.x, lane = tid & 63;
  const int g = lane >> 4, l15 = lane & 15;
  const int wid = blockIdx.x * 4 + (tid >> 6);
  const int nw  = gridDim.x * 4;
  const uint4* w1q = (const uint4*)w1b;          // 16 uint4 per row

  for (int it = wid; it < V / 4; it += nw) {
    const int r = it * 4 + g;
    int s = rowptr[r], e = rowptr[r + 1];

    float4* op = (float4*)(out + (size_t)r * 256) + l15 * 2;
    float4 o0 = op[0];                           // issue early; in flight
    float4 o1 = op[1];                           //   during the gather

    float a0=0.f,a1=0.f,a2=0.f,a3=0.f,a4=0.f,a5=0.f,a6=0.f,a7=0.f;
    int u = (s < e) ? adj[s] : 0;
    for (int j = s; j < e; ++j) {
      int un = adj[j + 1];                       // pad-safe prefetch
      uint4 d = w1q[(size_t)u * 16 + l15];
      a0 += bf_lo(d.x); a1 += bf_hi(d.x);
      a2 += bf_lo(d.y); a3 += bf_hi(d.y);
      a4 += bf_lo(d.z); a5 += bf_hi(d.z);
      a6 += bf_lo(d.w); a7 += bf_hi(d.w);
      u = un;
    }
    o0.x += a0; o0.y += a1; o0.z += a2; o0.w += a3;
    o1.x += a4; o1.y += a5; o1.z += a6; o1.w += a7;
    op[0] = o0; op[1] = o1;
  }
}

// ---------------------------------------------------------------------------
// CSR build
// ---------------------------------------------------------------------------
__global__ void count_deg(const int* __restrict__ edges, int* __restrict__ deg) {
  int i = blockIdx.x * blockDim.x + threadIdx.x;
  if (i >= 2 * E) return;
  int e = i >> 1, half = i & 1;
  atomicAdd(&deg[edges[2 * e + half]], 1);
}

__global__ void scan1(const int* __restrict__ deg, int* __restrict__ rowptr,
                      int* __restrict__ bsums) {
  __shared__ int sm[256];
  int i = blockIdx.x * 256 + threadIdx.x;
  int v = (i < V) ? deg[i] : 0;
  sm[threadIdx.x] = v;
  __syncthreads();
  for (int off = 1; off < 256; off <<= 1) {
    int t = (threadIdx.x >= off) ? sm[threadIdx.x - off] : 0;
    __syncthreads();
    sm[threadIdx.x] += t;
    __syncthreads();
  }
  if (i < V) rowptr[i] = sm[threadIdx.x] - v;
  if (threadIdx.x == 255) bsums[blockIdx.x] = sm[255];
}

__global__ void scan2(int* __restrict__ bsums) {
  __shared__ int sm[1024];
  int t = threadIdx.x;
  int v = (t < NB1) ? bsums[t] : 0;
  sm[t] = v;
  __syncthreads();
  for (int off = 1; off < 1024; off <<= 1) {
    int x = (t >= off) ? sm[t - off] : 0;
    __syncthreads();
    sm[t] += x;
    __syncthreads();
  }
  if (t < NB1) bsums[t] = sm[t] - v;
}

__global__ void scan3(int* __restrict__ rowptr, const int* __restrict__ bsums,
                      int* __restrict__ cursor) {
  int i = blockIdx.x * 256 + threadIdx.x;
  if (i < V) {
    int r = rowptr[i] + bsums[blockIdx.x];
    rowptr[i] = r;
    cursor[i] = r;
  }
  if (i == 0) rowptr[V] = 2 * E;
}

__global__ void fill_adj(const int* __restrict__ edges, int* __restrict__ cursor,
                         int* __restrict__ adj) {
  int i = blockIdx.x * blockDim.x + threadIdx.x;
  if (i >= 2 * E) return;
  int e = i >> 1, half = i & 1;
  int dst = edges[2 * e + half];
  int src = edges[2 * e + (half ^ 1)];
  adj[atomicAdd(&cursor[dst], 1)] = src;
}

// ---------------------------------------------------------------------------
extern "C" void kernel_launch(void* const* d_in, const int* in_sizes, int n_in,
                              void* d_out, int out_size, void* d_ws, size_t ws_size,
                              hipStream_t stream)
{
  const float* verts = (const float*)d_in[0];
  const int*   edges = (const int*)d_in[1];
  const float* w0_w  = (const float*)d_in[2];
  const float* w0_b  = (const float*)d_in[3];
  const float* w1_w  = (const float*)d_in[4];
  const float* w1_b  = (const float*)d_in[5];
  float* out = (float*)d_out;
  char*  ws  = (char*)d_ws;

  // workspace layout (bytes), total ~58.6 MB
  unsigned short* w1b = (unsigned short*)(ws);            // V*128*2 = 51,200,000
  int* rowptr = (int*)(ws + 51200000);                    // (V+1)*4
  int* cursor = (int*)(ws + 52000256);                    // V*4
  int* adj    = (int*)(ws + 52800256);                    // (2E+8)*4
  int* deg    = (int*)(ws + 57600288);                    // V*4
  int* bsums  = (int*)(ws + 58400288);                    // 1024*4
  unsigned short* Wb3 = (unsigned short*)(ws + 58404384); // 98304*2 = 196,608

  hipMemsetAsync(deg, 0, V * sizeof(int), stream);
  hipMemsetAsync(adj + 2 * E, 0, 8 * sizeof(int), stream);   // prefetch pad

  prep_w3<<<384, 256, 0, stream>>>(w0_w, w1_w, Wb3);

  count_deg<<<(2 * E + 255) / 256, 256, 0, stream>>>(edges, deg);
  scan1<<<NB1, 256, 0, stream>>>(deg, rowptr, bsums);
  scan2<<<1, 1024, 0, stream>>>(bsums);
  scan3<<<NB1, 256, 0, stream>>>(rowptr, bsums, cursor);
  fill_adj<<<(2 * E + 255) / 256, 256, 0, stream>>>(edges, cursor, adj);

  gemm_all<<<1042, 256, 0, stream>>>(verts, Wb3, w0_b, w1_b, out, w1b);

  gather_rmw<<<2048, 256, 0, stream>>>(rowptr, adj, w1b, out);
}

// Round 8
// 424.826 us; speedup vs baseline: 1.2238x; 1.2238x over previous
//
#include <hip/hip_runtime.h>
#include <hip/hip_bf16.h>
#include <stdint.h>

#define V 200000
#define E 600000
#define NB1 782          // ceil(V/256)

using bf16x8_t = __attribute__((ext_vector_type(8))) short;
using f32x4_t  = __attribute__((ext_vector_type(4))) float;

__device__ __forceinline__ unsigned short f2bf(float f) {
  __hip_bfloat16 h = __float2bfloat16(f);
  return *reinterpret_cast<unsigned short*>(&h);
}
__device__ __forceinline__ float bf_lo(unsigned d) { return __uint_as_float(d << 16); }
__device__ __forceinline__ float bf_hi(unsigned d) { return __uint_as_float(d & 0xffff0000u); }

// ---------------------------------------------------------------------------
// prep_w2: fragment-linear weights; B operands = coalesced 1KB loads from L2.
//   o = ((kg*24 + cg)*64 + lane)*8 + e ;  W[c][k], c=cg*16+(lane&15),
//   k = kg*32+(lane>>4)*8+e.  c<256 -> w0 ; c>=256 -> w1.
// ---------------------------------------------------------------------------
__global__ void prep_w2(const float* __restrict__ w0, const float* __restrict__ w1,
                        unsigned short* __restrict__ Wb2) {
  int o = blockIdx.x * 256 + threadIdx.x;        // 0..98303
  int kg = o / 12288;
  int r  = o - kg * 12288;
  int cg = r >> 9;
  int r2 = r & 511;
  int lane = r2 >> 3, e = r2 & 7;
  int c = cg * 16 + (lane & 15);
  int k = kg * 32 + (lane >> 4) * 8 + e;
  float v = (c < 256) ? w0[c * 256 + k] : w1[(c - 256) * 256 + k];
  Wb2[o] = f2bf(v);
}

// ---------------------------------------------------------------------------
// GEMM (round-3 proven structure): BM=64, 512 thr, A dbuf-LDS, B frag-linear.
// NEW frag map: waves 0-3 own w0 frags {4wv..4wv+3} (cols 64wv..+64);
// waves 4-7 own w1 frag PAIR {2j, 2j+1}, j=wv-4, and emit packed dwords:
//   w1s[row][16j + l15] = ( bf16(col 32j+l15), bf16(col 32j+16+l15) )
// so the gather can consume full rows as uint4 with float4-aligned unpack.
// ---------------------------------------------------------------------------
__global__ __launch_bounds__(512, 4) void gemm(
    const float* __restrict__ verts, const unsigned short* __restrict__ Wb2,
    const float* __restrict__ w0_b, const float* __restrict__ w1_b,
    float* __restrict__ out, unsigned int* __restrict__ w1s)
{
  __shared__ __align__(16) unsigned short As[2][64 * 64];   // 16 KB

  const int tid  = threadIdx.x;
  const int lane = tid & 63;
  const int wv   = tid >> 6;            // 0..7
  const int mBase = blockIdx.x * 64;

  const int srow  = tid >> 3;           // 0..63
  const int skseg = tid & 7;
  const float* vsrc = verts + (size_t)(mBase + srow) * 256 + skseg * 8;
  const int sW = srow * 64 + ((skseg ^ (srow & 7)) * 8);

  f32x4_t acc[4][4];
  #pragma unroll
  for (int m = 0; m < 4; ++m)
    #pragma unroll
    for (int n = 0; n < 4; ++n)
      acc[m][n] = (f32x4_t){0.f, 0.f, 0.f, 0.f};

  auto Aload = [&](int kb, float4* a) {
    a[0] = *(const float4*)(vsrc + kb * 64);
    a[1] = *(const float4*)(vsrc + kb * 64 + 4);
  };
  auto Awrite = [&](int b, const float4* a) {
    union { unsigned short us[8]; uint4 q; } p;
    p.us[0]=f2bf(a[0].x); p.us[1]=f2bf(a[0].y); p.us[2]=f2bf(a[0].z); p.us[3]=f2bf(a[0].w);
    p.us[4]=f2bf(a[1].x); p.us[5]=f2bf(a[1].y); p.us[6]=f2bf(a[1].z); p.us[7]=f2bf(a[1].w);
    *(uint4*)&As[b][sW] = p.q;
  };
  auto compute = [&](int b, int kb) {
    #pragma unroll
    for (int kc = 0; kc < 2; ++kc) {
      bf16x8_t af[4];
      #pragma unroll
      for (int m = 0; m < 4; ++m) {
        int row = m * 16 + (lane & 15);
        int seg = (kc * 4 + (lane >> 4)) ^ (row & 7);
        af[m] = *(const bf16x8_t*)&As[b][row * 64 + seg * 8];
      }
      int kg = kb * 2 + kc;
      if (wv < 4) {                                // w0: 4 frags
        #pragma unroll
        for (int n = 0; n < 4; ++n) {
          int f = kg * 24 + wv * 4 + n;
          bf16x8_t bfr = *(const bf16x8_t*)(Wb2 + (size_t)f * 512 + lane * 8);
          #pragma unroll
          for (int m = 0; m < 4; ++m)
            acc[m][n] = __builtin_amdgcn_mfma_f32_16x16x32_bf16(
                af[m], bfr, acc[m][n], 0, 0, 0);
        }
      } else {                                     // w1: frag pair
        #pragma unroll
        for (int n = 0; n < 2; ++n) {
          int f = kg * 24 + 16 + (wv - 4) * 2 + n;
          bf16x8_t bfr = *(const bf16x8_t*)(Wb2 + (size_t)f * 512 + lane * 8);
          #pragma unroll
          for (int m = 0; m < 4; ++m)
            acc[m][n] = __builtin_amdgcn_mfma_f32_16x16x32_bf16(
                af[m], bfr, acc[m][n], 0, 0, 0);
        }
      }
    }
  };

  { float4 a0[2]; Aload(0, a0); Awrite(0, a0); }
  __syncthreads();

  int buf = 0;
  #pragma unroll
  for (int kb = 0; kb < 3; ++kb) {
    float4 an[2];
    Aload(kb + 1, an);          // issue early: latency hides under compute
    compute(buf, kb);
    Awrite(buf ^ 1, an);
    __syncthreads();
    buf ^= 1;
  }
  compute(buf, 3);

  // epilogue: C/D layout col = lane&15, row = (lane>>4)*4 + r
  const int l15 = lane & 15, lq = lane >> 4;
  if (wv < 4) {
    #pragma unroll
    for (int n = 0; n < 4; ++n) {
      int col = wv * 64 + n * 16 + l15;
      float bias = w0_b[col];
      #pragma unroll
      for (int m = 0; m < 4; ++m) {
        int rb = mBase + m * 16 + lq * 4;
        #pragma unroll
        for (int r = 0; r < 4; ++r)
          out[(size_t)(rb + r) * 256 + col] = acc[m][n][r] + bias;
      }
    }
  } else {
    int j = wv - 4;
    float bias0 = w1_b[32 * j + l15];
    float bias1 = w1_b[32 * j + 16 + l15];
    #pragma unroll
    for (int m = 0; m < 4; ++m) {
      int rb = mBase + m * 16 + lq * 4;
      #pragma unroll
      for (int r = 0; r < 4; ++r) {
        unsigned pw = (unsigned)f2bf(acc[m][0][r] + bias0)
                    | ((unsigned)f2bf(acc[m][1][r] + bias1) << 16);
        w1s[(size_t)(rb + r) * 64 + 16 * j + l15] = pw;
      }
    }
  }
}

// ---------------------------------------------------------------------------
// gather_rmw: out[r, 0:128] += segment-sum of packed w1s rows.
// 16-lane group per row; uint4 row reads (256B coalesced); 2 rows in flight
// per chain; out RMW as two float4s per lane covering whole 64B lines.
// Unpack: lane l15, dword q: lo -> col 32*(l15>>2)+4*(l15&3)+q, hi -> +16.
// ---------------------------------------------------------------------------
__global__ __launch_bounds__(256, 8) void gather_rmw(
    const int* __restrict__ rowptr, const int* __restrict__ adj,
    const unsigned int* __restrict__ w1s, float* __restrict__ out)
{
  const int tid = threadIdx.x, lane = tid & 63;
  const int g = lane >> 4, l15 = lane & 15;
  const int wid = blockIdx.x * 4 + (tid >> 6);
  const int nw  = gridDim.x * 4;
  const uint4* w1q = (const uint4*)w1s;          // 16 uint4 per row
  const int o0i = 8 * (l15 >> 2) + (l15 & 3);    // float4 index in out row

  for (int it = wid; it < V / 4; it += nw) {
    const int r = it * 4 + g;
    int s = rowptr[r], e = rowptr[r + 1];

    float4* opb = (float4*)(out + (size_t)r * 256);
    float4 o0 = opb[o0i];
    float4 o1 = opb[o0i + 4];

    float a0=0.f,a1=0.f,a2=0.f,a3=0.f,a4=0.f,a5=0.f,a6=0.f,a7=0.f;
    int u0 = adj[s], u1 = adj[s + 1];            // pad-safe
    int j = s;
    for (; j + 2 <= e; j += 2) {
      uint4 d0 = w1q[(size_t)u0 * 16 + l15];
      uint4 d1 = w1q[(size_t)u1 * 16 + l15];
      u0 = adj[j + 2]; u1 = adj[j + 3];          // prefetch next pair
      a0 += bf_lo(d0.x) + bf_lo(d1.x);  a4 += bf_hi(d0.x) + bf_hi(d1.x);
      a1 += bf_lo(d0.y) + bf_lo(d1.y);  a5 += bf_hi(d0.y) + bf_hi(d1.y);
      a2 += bf_lo(d0.z) + bf_lo(d1.z);  a6 += bf_hi(d0.z) + bf_hi(d1.z);
      a3 += bf_lo(d0.w) + bf_lo(d1.w);  a7 += bf_hi(d0.w) + bf_hi(d1.w);
    }
    if (j < e) {
      uint4 d = w1q[(size_t)u0 * 16 + l15];
      a0 += bf_lo(d.x);  a4 += bf_hi(d.x);
      a1 += bf_lo(d.y);  a5 += bf_hi(d.y);
      a2 += bf_lo(d.z);  a6 += bf_hi(d.z);
      a3 += bf_lo(d.w);  a7 += bf_hi(d.w);
    }
    o0.x += a0; o0.y += a1; o0.z += a2; o0.w += a3;
    o1.x += a4; o1.y += a5; o1.z += a6; o1.w += a7;
    opb[o0i]     = o0;
    opb[o0i + 4] = o1;
  }
}

// ---------------------------------------------------------------------------
// CSR build
// ---------------------------------------------------------------------------
__global__ void count_deg(const int* __restrict__ edges, int* __restrict__ deg) {
  int i = blockIdx.x * blockDim.x + threadIdx.x;
  if (i >= 2 * E) return;
  int e = i >> 1, half = i & 1;
  atomicAdd(&deg[edges[2 * e + half]], 1);
}

__global__ void scan1(const int* __restrict__ deg, int* __restrict__ rowptr,
                      int* __restrict__ bsums) {
  __shared__ int sm[256];
  int i = blockIdx.x * 256 + threadIdx.x;
  int v = (i < V) ? deg[i] : 0;
  sm[threadIdx.x] = v;
  __syncthreads();
  for (int off = 1; off < 256; off <<= 1) {
    int t = (threadIdx.x >= off) ? sm[threadIdx.x - off] : 0;
    __syncthreads();
    sm[threadIdx.x] += t;
    __syncthreads();
  }
  if (i < V) rowptr[i] = sm[threadIdx.x] - v;
  if (threadIdx.x == 255) bsums[blockIdx.x] = sm[255];
}

__global__ void scan2(int* __restrict__ bsums) {
  __shared__ int sm[1024];
  int t = threadIdx.x;
  int v = (t < NB1) ? bsums[t] : 0;
  sm[t] = v;
  __syncthreads();
  for (int off = 1; off < 1024; off <<= 1) {
    int x = (t >= off) ? sm[t - off] : 0;
    __syncthreads();
    sm[t] += x;
    __syncthreads();
  }
  if (t < NB1) bsums[t] = sm[t] - v;
}

__global__ void scan3(int* __restrict__ rowptr, const int* __restrict__ bsums,
                      int* __restrict__ cursor) {
  int i = blockIdx.x * 256 + threadIdx.x;
  if (i < V) {
    int r = rowptr[i] + bsums[blockIdx.x];
    rowptr[i] = r;
    cursor[i] = r;
  }
  if (i == 0) rowptr[V] = 2 * E;
}

__global__ void fill_adj(const int* __restrict__ edges, int* __restrict__ cursor,
                         int* __restrict__ adj) {
  int i = blockIdx.x * blockDim.x + threadIdx.x;
  if (i >= 2 * E) return;
  int e = i >> 1, half = i & 1;
  int dst = edges[2 * e + half];
  int src = edges[2 * e + (half ^ 1)];
  adj[atomicAdd(&cursor[dst], 1)] = src;
}

// ---------------------------------------------------------------------------
extern "C" void kernel_launch(void* const* d_in, const int* in_sizes, int n_in,
                              void* d_out, int out_size, void* d_ws, size_t ws_size,
                              hipStream_t stream)
{
  const float* verts = (const float*)d_in[0];
  const int*   edges = (const int*)d_in[1];
  const float* w0_w  = (const float*)d_in[2];
  const float* w0_b  = (const float*)d_in[3];
  const float* w1_w  = (const float*)d_in[4];
  const float* w1_b  = (const float*)d_in[5];
  float* out = (float*)d_out;
  char*  ws  = (char*)d_ws;

  // workspace layout (bytes), total ~58.6 MB
  unsigned int* w1s = (unsigned int*)(ws);                // V*64*4 = 51,200,000
  int* rowptr = (int*)(ws + 51200000);                    // (V+1)*4
  int* cursor = (int*)(ws + 52000256);                    // V*4
  int* adj    = (int*)(ws + 52800256);                    // (2E+8)*4
  int* deg    = (int*)(ws + 57600288);                    // V*4
  int* bsums  = (int*)(ws + 58400288);                    // 1024*4
  unsigned short* Wb2 = (unsigned short*)(ws + 58404384); // 98304*2 = 196,608

  hipMemsetAsync(deg, 0, V * sizeof(int), stream);
  hipMemsetAsync(adj + 2 * E, 0, 8 * sizeof(int), stream);   // prefetch pad

  prep_w2<<<384, 256, 0, stream>>>(w0_w, w1_w, Wb2);

  count_deg<<<(2 * E + 255) / 256, 256, 0, stream>>>(edges, deg);
  scan1<<<NB1, 256, 0, stream>>>(deg, rowptr, bsums);
  scan2<<<1, 1024, 0, stream>>>(bsums);
  scan3<<<NB1, 256, 0, stream>>>(rowptr, bsums, cursor);
  fill_adj<<<(2 * E + 255) / 256, 256, 0, stream>>>(edges, cursor, adj);

  gemm<<<V / 64, 512, 0, stream>>>(verts, Wb2, w0_b, w1_b, out, w1s);

  gather_rmw<<<2048, 256, 0, stream>>>(rowptr, adj, w1s, out);
}